// Round 2
// baseline (2285.992 us; speedup 1.0000x reference)
//
#include <hip/hip_runtime.h>
#include <hip/hip_bf16.h>
#include <math.h>

// Problem dims (DAGNN_14594298872388)
#define NN     100000   // nodes
#define INDIM  500
#define HID    256
#define NCLASS 50
#define KHOPS  10
#define KPAD   512      // INDIM padded to multiple of 32 for MFMA
#define CPAD   64       // NCLASS padded (32 packed bf16 pairs per node row)

static inline size_t roundup256(size_t x) { return (x + 255) & ~(size_t)255; }

typedef __attribute__((ext_vector_type(8))) short bf16x8;   // 8 bf16 = 4 VGPRs
typedef __attribute__((ext_vector_type(4))) float f32x4;    // MFMA acc
typedef __attribute__((ext_vector_type(4))) short short4v;

typedef __attribute__((address_space(3))) unsigned       lds_u32;
typedef const __attribute__((address_space(1))) unsigned glb_u32;

__device__ inline short f2bf(float f) {      // fp32 -> bf16, round-nearest-even
    union { float f; unsigned u; } v; v.f = f;
    unsigned r = v.u + 0x7FFFu + ((v.u >> 16) & 1u);
    return (short)(r >> 16);
}
__device__ inline short f2bf_hw(float f) {   // HW cvt (compiler emits v_cvt_pk)
    __hip_bfloat16 h = __float2bfloat16(f);
    return *reinterpret_cast<short*>(&h);
}
__device__ inline float bflo(unsigned u) {   // low bf16 of packed pair -> fp32
    union { unsigned u; float f; } v; v.u = u << 16; return v.f;
}
__device__ inline float bfhi(unsigned u) {   // high bf16 of packed pair -> fp32
    union { unsigned u; float f; } v; v.u = u & 0xFFFF0000u; return v.f;
}
__device__ inline unsigned packbf(float a, float b) {
    return (unsigned)(unsigned short)f2bf(a) | ((unsigned)(unsigned short)f2bf(b) << 16);
}

// ---------------------------------------------------------------------------
// prep: zero counters, degree, norm, scan, CSR fill
// ---------------------------------------------------------------------------
__global__ void dagnn_zero2(int* __restrict__ a, int* __restrict__ b, int n) {
    int i = blockIdx.x * blockDim.x + threadIdx.x;
    if (i < n) { a[i] = 0; b[i] = 0; }
}

__global__ void dagnn_deg(const int* __restrict__ dst, int* __restrict__ degi, int E) {
    int e = blockIdx.x * blockDim.x + threadIdx.x;
    if (e < E) atomicAdd(&degi[dst[e]], 1);
}

__global__ void dagnn_norm(const int* __restrict__ degi, float* __restrict__ nrm, int n) {
    int i = blockIdx.x * blockDim.x + threadIdx.x;
    if (i < n) nrm[i] = rsqrtf((float)degi[i]);   // deg >= 1 (self loop)
}

__global__ void dagnn_scan(const int* __restrict__ degi, int* __restrict__ rowptr, int n) {
    __shared__ int wsum[16];
    __shared__ int carry_s;
    const int tid  = threadIdx.x;        // 1024
    const int lane = tid & 63;
    const int wid  = tid >> 6;
    if (tid == 0) carry_s = 0;
    __syncthreads();
    for (int base = 0; base < n; base += 4096) {
        int i0 = base + tid * 4;
        int v0 = (i0 + 0 < n) ? degi[i0 + 0] : 0;
        int v1 = (i0 + 1 < n) ? degi[i0 + 1] : 0;
        int v2 = (i0 + 2 < n) ? degi[i0 + 2] : 0;
        int v3 = (i0 + 3 < n) ? degi[i0 + 3] : 0;
        int tsum = v0 + v1 + v2 + v3;
        int x = tsum;
        #pragma unroll
        for (int off = 1; off < 64; off <<= 1) {
            int t = __shfl_up(x, off);
            if (lane >= off) x += t;
        }
        if (lane == 63) wsum[wid] = x;
        __syncthreads();
        if (tid == 0) {
            int run = carry_s;
            #pragma unroll
            for (int w = 0; w < 16; ++w) { int t = wsum[w]; wsum[w] = run; run += t; }
            carry_s = run;
        }
        __syncthreads();
        int texcl = wsum[wid] + (x - tsum);
        if (i0 + 0 < n) rowptr[i0 + 0] = texcl;
        if (i0 + 1 < n) rowptr[i0 + 1] = texcl + v0;
        if (i0 + 2 < n) rowptr[i0 + 2] = texcl + v0 + v1;
        if (i0 + 3 < n) rowptr[i0 + 3] = texcl + v0 + v1 + v2;
        __syncthreads();
    }
    if (tid == 0) rowptr[n] = carry_s;
}

__global__ void dagnn_fill(const int* __restrict__ src, const int* __restrict__ dst,
                           const int* __restrict__ rowptr, int* __restrict__ fillc,
                           int* __restrict__ colidx, int E) {
    int e = blockIdx.x * blockDim.x + threadIdx.x;
    if (e >= E) return;
    int d = dst[e];
    int pos = rowptr[d] + atomicAdd(&fillc[d], 1);
    colidx[pos] = src[e];
}

// ---------------------------------------------------------------------------
// W1 [500][256] fp32 -> Bts: per-K-step pre-tiled bf16 layout.
// Tile ks (0..15) is a contiguous 16 KB slab: [n 0..255][k' 0..31],
// value = W1[ks*32+k'][n], zero-padded for k >= 500.
// ---------------------------------------------------------------------------
__global__ void dagnn_w1ts(const float* __restrict__ W1, short* __restrict__ Bts) {
    int idx = blockIdx.x * 256 + threadIdx.x;   // 16*256*32 = 131072
    if (idx >= HID * KPAD) return;
    int ks = idx >> 13;          // K-step  0..15
    int n  = (idx >> 5) & 255;   // col     0..255
    int kk = idx & 31;           // k-in-tile
    int k  = ks * 32 + kk;
    float v = (k < INDIM) ? W1[(size_t)k * HID + n] : 0.f;
    Bts[idx] = f2bf(v);
}

// ---------------------------------------------------------------------------
// W2 [256][50] fp32 -> W2t [64][256] bf16 (transposed, zero-padded N)
// ---------------------------------------------------------------------------
__global__ void dagnn_w2t(const float* __restrict__ W2, short* __restrict__ W2t) {
    int idx = blockIdx.x * 256 + threadIdx.x;   // 64*256 = 16384
    if (idx >= CPAD * HID) return;
    int n = idx >> 8;         // 0..63
    int k = idx & 255;        // 0..255
    float v = (n < NCLASS) ? W2[(size_t)k * NCLASS + n] : 0.f;
    W2t[idx] = f2bf(v);
}

// sgate[c] = (s[2c], s[2c+1]) zero-padded; 32 entries
__global__ void dagnn_sgate(const float* __restrict__ svec, float2* __restrict__ sg) {
    int c = threadIdx.x;
    if (c < 32) {
        float x = (2 * c     < NCLASS) ? svec[2 * c]     : 0.f;
        float y = (2 * c + 1 < NCLASS) ? svec[2 * c + 1] : 0.f;
        sg[c] = make_float2(x, y);
    }
}

// ---------------------------------------------------------------------------
// GEMM1 (MFMA bf16): hid = relu(feats @ W1 + b1), bf16 out.
// 2-phase global_load_lds pipeline; A fp32 staged with XOR chunk-swizzle on
// the global source (linear LDS dest), matching XOR on the ds_read side;
// B staged from the pre-tiled Bts slab. Epilogue via LDS for 16B stores.
// block = 512 threads (8 waves); tile 128(M) x 256(N); BK=32.
// ---------------------------------------------------------------------------
#define G1_STAGE(ABASE, BBASE, KS)                                             \
    {                                                                          \
        const int k0_ = (KS) * 32;                                             \
        _Pragma("unroll")                                                      \
        for (int j = 0; j < 2; ++j) {                                          \
            int slot = (wid * 2 + j) * 64 + lane;                              \
            int mrow = slot >> 3;                 /* 0..127 */                 \
            int q    = (slot & 7) ^ (mrow & 7);   /* source chunk (swizzle) */ \
            int gm   = row0 + mrow;                                            \
            int gk   = k0_ + q * 4;                                            \
            const float* asrc = (gm < M && gk < INDIM)                         \
                ? (A + (size_t)gm * INDIM + gk) : A;                           \
            __builtin_amdgcn_global_load_lds((glb_u32*)asrc,                   \
                (lds_u32*)((ABASE) + (wid * 2 + j) * 256), 16, 0, 0);          \
            const short* bsrc = Bts + ((size_t)(KS) << 13) + slot * 8;         \
            __builtin_amdgcn_global_load_lds((glb_u32*)bsrc,                   \
                (lds_u32*)((BBASE) + (wid * 2 + j) * 512), 16, 0, 0);          \
        }                                                                      \
    }

__global__ __launch_bounds__(512, 4) void dagnn_gemm1_mfma(
        const float* __restrict__ A, const short* __restrict__ Bts,
        const float* __restrict__ bias, short* __restrict__ C, int M) {
    __shared__ __align__(16) char smem[67584];   // max(staging 64K, epi 66K)
    float* As0 = (float*)smem;                   // [128][32] f32, 16 KB
    float* As1 = (float*)(smem + 16384);
    short* Bs0 = (short*)(smem + 32768);         // [256][32] bf16, 16 KB
    short* Bs1 = (short*)(smem + 49152);
    short* Ep  = (short*)smem;                   // epilogue: [128][264] bf16

    const int tid  = threadIdx.x;
    const int lane = tid & 63;
    const int wid  = tid >> 6;              // 0..7
    const int l16  = lane & 15;
    const int quad = lane >> 4;             // 0..3
    const int m_off = (wid & 1) * 64;
    const int n_off = (wid >> 1) * 64;
    const int row0  = blockIdx.x * 128;

    f32x4 acc[4][4] = {};

    G1_STAGE(As0, Bs0, 0)
    __syncthreads();

    for (int ks = 0; ks < KPAD / 32; ++ks) {
        const int cur = ks & 1;
        const float* ab = cur ? As1 : As0;
        const short* bb = cur ? Bs1 : Bs0;
        if (ks + 1 < KPAD / 32) {
            if (cur) { G1_STAGE(As0, Bs0, ks + 1) }
            else     { G1_STAGE(As1, Bs1, ks + 1) }
        }

        bf16x8 bfr[4];
        #pragma unroll
        for (int nt = 0; nt < 4; ++nt)
            bfr[nt] = *(const bf16x8*)(bb + (n_off + nt * 16 + l16) * 32 + quad * 8);

        #pragma unroll
        for (int mt = 0; mt < 4; ++mt) {
            int m  = m_off + mt * 16 + l16;
            int s0 = (quad * 2 + 0) ^ (m & 7);       // swizzled chunk slots
            int s1 = (quad * 2 + 1) ^ (m & 7);
            float4 lo = *(const float4*)(ab + m * 32 + s0 * 4);
            float4 hi = *(const float4*)(ab + m * 32 + s1 * 4);
            bf16x8 af;
            af[0] = f2bf_hw(lo.x); af[1] = f2bf_hw(lo.y);
            af[2] = f2bf_hw(lo.z); af[3] = f2bf_hw(lo.w);
            af[4] = f2bf_hw(hi.x); af[5] = f2bf_hw(hi.y);
            af[6] = f2bf_hw(hi.z); af[7] = f2bf_hw(hi.w);
            #pragma unroll
            for (int nt = 0; nt < 4; ++nt)
                acc[mt][nt] = __builtin_amdgcn_mfma_f32_16x16x32_bf16(
                                  af, bfr[nt], acc[mt][nt], 0, 0, 0);
        }
        __syncthreads();      // drains vmcnt(0): next buffer staged + LDS free
    }

    // epilogue: bias + relu -> packed bf16 pairs into LDS, then coalesced out
    float bv[4];
    #pragma unroll
    for (int nt = 0; nt < 4; ++nt) bv[nt] = bias[n_off + nt * 16 + l16];

    #pragma unroll
    for (int mt = 0; mt < 4; ++mt) {
        #pragma unroll
        for (int nt = 0; nt < 4; ++nt) {
            #pragma unroll
            for (int r = 0; r < 4; ++r) {
                float v = acc[mt][nt][r] + bv[nt];
                v = v > 0.f ? v : 0.f;
                float vp = __shfl_xor(v, 1);          // partner column's value
                if (!(l16 & 1)) {
                    int mrel = m_off + mt * 16 + quad * 4 + r;
                    *(unsigned*)(Ep + mrel * 264 + n_off + nt * 16 + l16) =
                        packbf(v, vp);
                }
            }
        }
    }
    __syncthreads();
    #pragma unroll
    for (int it = 0; it < 8; ++it) {
        int cidx = tid + it * 512;          // 128 rows x 32 chunks of 16 B
        int rr   = cidx >> 5;
        int chk  = cidx & 31;
        int gm   = row0 + rr;
        if (gm < M)
            *(bf16x8*)(C + (size_t)gm * HID + chk * 8) =
                *(const bf16x8*)(Ep + rr * 264 + chk * 8);
    }
}

// ---------------------------------------------------------------------------
// GEMM2 (MFMA) + gate epilogue:
//   x = hid(bf16) @ W2 + b2 ; hs0 = packed-bf16(x*nrm) GROUPED ; out = S0*x
// hs grouped layout: hs[g][node][j], g = pair-group (8 u32 = 32 B per node).
// block = 256 threads (4 waves); tile 128(M) x 64(N); K=256, BK=64
// ---------------------------------------------------------------------------
#define A2_STRIDE 72
#define B2_STRIDE 264
__global__ __launch_bounds__(256) void dagnn_mlp2_mfma(
        const short* __restrict__ hid, const short* __restrict__ W2t,
        const float* __restrict__ b2, const float* __restrict__ svec,
        const float* __restrict__ nrm,
        unsigned* __restrict__ hs0, float* __restrict__ out, int M) {
    __shared__ __align__(16) short As[128 * A2_STRIDE];
    __shared__ __align__(16) short Bs[CPAD * B2_STRIDE];

    const int tid  = threadIdx.x;
    const int lane = tid & 63;
    const int wid  = tid >> 6;              // 0..3
    const int l16  = lane & 15;
    const int quad = lane >> 4;
    const int m_off = wid * 32;
    const int row0  = blockIdx.x * 128;

    // stage all of W2t (64 x 256) into LDS once
    #pragma unroll
    for (int it = 0; it < 8; ++it) {
        int slot = tid + it * 256;          // 0..2047
        int n   = slot >> 5;                // 0..63
        int seg = slot & 31;                // 8 bf16 each
        bf16x8 b = *(const bf16x8*)(W2t + (size_t)n * HID + seg * 8);
        *(bf16x8*)&Bs[n * B2_STRIDE + seg * 8] = b;
    }

    f32x4 acc[2][4] = {};

    for (int ks = 0; ks < HID / 64; ++ks) {     // 4 iterations, BK=64
        const int k0 = ks * 64;
        #pragma unroll
        for (int it = 0; it < 4; ++it) {
            int slot = tid + it * 256;      // 0..1023
            int m   = slot >> 3;            // 0..127
            int seg = slot & 7;             // 8 bf16 each
            int gm  = row0 + m;
            bf16x8 v = {};
            if (gm < M) v = *(const bf16x8*)(hid + (size_t)gm * HID + k0 + seg * 8);
            *(bf16x8*)&As[m * A2_STRIDE + seg * 8] = v;
        }
        __syncthreads();

        #pragma unroll
        for (int ksub = 0; ksub < 2; ++ksub) {
            bf16x8 af[2], bfr[4];
            #pragma unroll
            for (int mt = 0; mt < 2; ++mt)
                af[mt] = *(const bf16x8*)&As[(m_off + mt * 16 + l16) * A2_STRIDE
                                             + ksub * 32 + quad * 8];
            #pragma unroll
            for (int nt = 0; nt < 4; ++nt)
                bfr[nt] = *(const bf16x8*)&Bs[(nt * 16 + l16) * B2_STRIDE
                                              + k0 + ksub * 32 + quad * 8];
            #pragma unroll
            for (int mt = 0; mt < 2; ++mt)
                #pragma unroll
                for (int nt = 0; nt < 4; ++nt)
                    acc[mt][nt] = __builtin_amdgcn_mfma_f32_16x16x32_bf16(
                                      af[mt], bfr[nt], acc[mt][nt], 0, 0, 0);
        }
        __syncthreads();
    }

    float b2v[4], ssv[4];
    #pragma unroll
    for (int nt = 0; nt < 4; ++nt) {
        int gc = nt * 16 + l16;
        b2v[nt] = (gc < NCLASS) ? b2[gc]   : 0.f;
        ssv[nt] = (gc < NCLASS) ? svec[gc] : 0.f;
    }
    #pragma unroll
    for (int mt = 0; mt < 2; ++mt) {
        #pragma unroll
        for (int r = 0; r < 4; ++r) {
            int gm = row0 + m_off + mt * 16 + quad * 4 + r;
            float xv[4], q = 0.f;
            #pragma unroll
            for (int nt = 0; nt < 4; ++nt) {
                xv[nt] = acc[mt][nt][r] + b2v[nt];
                q += xv[nt] * ssv[nt];
            }
            #pragma unroll
            for (int off = 1; off < 16; off <<= 1) q += __shfl_xor(q, off);
            float S = 1.f / (1.f + __expf(-q));
            float nd = (gm < M) ? nrm[gm] : 0.f;
            #pragma unroll
            for (int nt = 0; nt < 4; ++nt) {
                int gc = nt * 16 + l16;
                float hv = xv[nt] * nd;
                float hp = __shfl_xor(hv, 1);     // partner lane's value
                if (gm < M) {
                    if (!(l16 & 1))               // grouped: g = nt, j = l16/2
                        hs0[(size_t)nt * M * 8 + (size_t)gm * 8 + (l16 >> 1)] =
                            packbf(hv, hp);
                    if (gc < NCLASS) out[(size_t)gm * NCLASS + gc] = S * xv[nt];
                }
            }
        }
    }
}

// ---------------------------------------------------------------------------
// grouped propagation hop. Channel-split: 4 groups x 32 B/node; each group's
// gather buffer is 3.2 MB -> L2-resident per XCD. Grid is group-major so
// in-order block dispatch keeps one group hot at a time. Writes per hop:
//   hs_next (bf16, for next hop's gather), rbuf (f32 r values, for finalize),
//   pp (per-group gate partials). out accumulation deferred to dagnn_final.
// One wave per (dst row, group); lanes = 8 edge-slots x 8 u32-channels.
// Non-temporal on streams to protect L2 residency of hs.
// ---------------------------------------------------------------------------
__global__ __launch_bounds__(256) void dagnn_propg(
        const unsigned* __restrict__ hs, const float* __restrict__ nrm,
        const int* __restrict__ rowptr, const int* __restrict__ colidx,
        const float2* __restrict__ sgate, unsigned* __restrict__ hs_next,
        float* __restrict__ rbuf, float* __restrict__ pp, int M, int nb) {
    const int wid  = threadIdx.x >> 6;
    const int lane = threadIdx.x & 63;
    const int g    = blockIdx.x / nb;       // group-major dispatch order
    const int bb   = blockIdx.x - g * nb;
    const int d    = bb * 4 + wid;
    if (d >= M) return;
    const int e8 = lane >> 3;               // edge slot 0..7
    const int j  = lane & 7;                // u32 index within group
    const int beg = rowptr[d];
    const int deg = rowptr[d + 1] - beg;
    const float nd = nrm[d];
    const unsigned* hsg = hs + (size_t)g * M * 8;

    float a0 = 0.f, a1 = 0.f;
    int sA = -1;
    if (e8 < deg) sA = __builtin_nontemporal_load(&colidx[beg + e8]);
    for (int i = 0; i < deg; i += 8) {
        int sB = -1;
        int nx = i + 8 + e8;
        if (nx < deg) sB = __builtin_nontemporal_load(&colidx[beg + nx]);
        if (sA >= 0) {
            unsigned u = hsg[(size_t)sA * 8 + j];
            a0 += bflo(u); a1 += bfhi(u);
        }
        sA = sB;
    }
    // reduce across the 8 edge slots (butterfly -> all lanes hold totals)
    #pragma unroll
    for (int off = 8; off < 64; off <<= 1) {
        a0 += __shfl_xor(a0, off);
        a1 += __shfl_xor(a1, off);
    }
    float r0 = a0 * nd, r1 = a1 * nd;
    float2 gt = sgate[g * 8 + j];
    float q = r0 * gt.x + r1 * gt.y;
    #pragma unroll
    for (int off = 1; off < 8; off <<= 1) q += __shfl_xor(q, off);

    if (lane < 8) {     // e8 == 0 octet writes the row outputs
        unsigned pk = packbf(r0 * nd, r1 * nd);
        __builtin_nontemporal_store(pk,
            &hs_next[(size_t)g * M * 8 + (size_t)d * 8 + j]);
        __builtin_nontemporal_store(r0, &rbuf[(size_t)d * 64 + g * 16 + 2 * j]);
        __builtin_nontemporal_store(r1, &rbuf[(size_t)d * 64 + g * 16 + 2 * j + 1]);
        if (j == 0)
            __builtin_nontemporal_store(q, &pp[(size_t)d * 4 + g]);
    }
}

// ---------------------------------------------------------------------------
// finalize: out[d][ch] += sum_k sigmoid(sum_g pp_k[d][g]) * rbuf_k[d][ch]
// one wave per node; fully-unrolled 10-hop accumulation (f32 exact r values).
// ---------------------------------------------------------------------------
__global__ __launch_bounds__(256) void dagnn_final(
        const float* __restrict__ rbuf, const float* __restrict__ pp,
        float* __restrict__ out, int M) {
    const int wid  = threadIdx.x >> 6;
    const int lane = threadIdx.x & 63;
    const int d = blockIdx.x * 4 + wid;
    if (d >= M) return;
    float acc = 0.f;
    #pragma unroll
    for (int k = 0; k < KHOPS; ++k) {
        const float4 pv = *(const float4*)&pp[(size_t)k * M * 4 + (size_t)d * 4];
        float p = (pv.x + pv.y) + (pv.z + pv.w);
        float S = 1.f / (1.f + __expf(-p));
        float r = rbuf[(size_t)k * M * 64 + (size_t)d * 64 + lane];
        acc += S * r;
    }
    if (lane < NCLASS)
        out[(size_t)d * NCLASS + lane] += acc;
}

// ---------------------------------------------------------------------------
extern "C" void kernel_launch(void* const* d_in, const int* in_sizes, int n_in,
                              void* d_out, int out_size, void* d_ws, size_t ws_size,
                              hipStream_t stream) {
    const float* feats = (const float*)d_in[0];
    const float* W1    = (const float*)d_in[1];
    const float* b1    = (const float*)d_in[2];
    const float* W2    = (const float*)d_in[3];
    const float* b2    = (const float*)d_in[4];
    const float* svec  = (const float*)d_in[5];
    const int*   src   = (const int*)d_in[6];
    const int*   dst   = (const int*)d_in[7];
    float* out = (float*)d_out;

    const int M = in_sizes[0] / INDIM;    // 100000
    const int E = in_sizes[6];            // 1600000

    // workspace carve-up
    char* p = (char*)d_ws;
    size_t off = 0;
    short*    hid   = (short*)   (p + off); off += roundup256((size_t)M * HID * 2);
    unsigned* hsA   = (unsigned*)(p + off); off += roundup256((size_t)M * 32 * 4);
    unsigned* hsB   = (unsigned*)(p + off); off += roundup256((size_t)M * 32 * 4);
    short*    W1t   = (short*)   (p + off); off += roundup256((size_t)HID * KPAD * 2);
    short*    W2t   = (short*)   (p + off); off += roundup256((size_t)CPAD * HID * 2);
    float2*   sgate = (float2*)  (p + off); off += roundup256(32 * sizeof(float2));
    int*      degi  = (int*)     (p + off); off += roundup256((size_t)M * 4);
    float*    nrm   = (float*)   (p + off); off += roundup256((size_t)M * 4);
    int*      rowptr= (int*)     (p + off); off += roundup256((size_t)(M + 1) * 4);
    int*      fillc = (int*)     (p + off); off += roundup256((size_t)M * 4);
    int*      colidx= (int*)     (p + off); off += roundup256((size_t)E * 4);
    float*    rbuf  = (float*)   (p + off); off += roundup256((size_t)KHOPS * M * 64 * 4);
    float*    pp    = (float*)   (p + off); off += roundup256((size_t)KHOPS * M * 4 * 4);
    (void)ws_size;

    // --- graph/degree prep ---
    dagnn_zero2<<<(M + 255) / 256, 256, 0, stream>>>(degi, fillc, M);
    dagnn_deg<<<(E + 255) / 256, 256, 0, stream>>>(dst, degi, E);
    dagnn_norm<<<(M + 255) / 256, 256, 0, stream>>>(degi, nrm, M);
    dagnn_scan<<<1, 1024, 0, stream>>>(degi, rowptr, M);
    dagnn_fill<<<(E + 255) / 256, 256, 0, stream>>>(src, dst, rowptr, fillc, colidx, E);

    // --- weight prep ---
    dagnn_w1ts<<<(HID * KPAD + 255) / 256, 256, 0, stream>>>(W1, W1t);
    dagnn_w2t<<<(CPAD * HID + 255) / 256, 256, 0, stream>>>(W2, W2t);
    dagnn_sgate<<<1, 32, 0, stream>>>(svec, sgate);

    // --- MLP ---
    dagnn_gemm1_mfma<<<(M + 127) / 128, 512, 0, stream>>>(feats, W1t, b1, hid, M);
    dagnn_mlp2_mfma<<<(M + 127) / 128, 256, 0, stream>>>(hid, W2t, b2, svec, nrm,
                                                         hsA, out, M);

    // --- K propagation hops (grouped, L2-resident gathers) ---
    const int nb = (M + 3) / 4;
    unsigned* hin = hsA;
    unsigned* hout = hsB;
    for (int k = 0; k < KHOPS; ++k) {
        dagnn_propg<<<4 * nb, 256, 0, stream>>>(hin, nrm, rowptr, colidx, sgate,
                                                hout,
                                                rbuf + (size_t)k * M * 64,
                                                pp   + (size_t)k * M * 4,
                                                M, nb);
        unsigned* t = hin; hin = hout; hout = t;
    }
    // --- fold hop contributions into out ---
    dagnn_final<<<(M + 3) / 4, 256, 0, stream>>>(rbuf, pp, out, M);
}

// Round 3
// 1167.182 us; speedup vs baseline: 1.9586x; 1.9586x over previous
//
#include <hip/hip_runtime.h>
#include <hip/hip_bf16.h>
#include <math.h>

// Problem dims (DAGNN_14594298872388)
#define NN     100000   // nodes
#define INDIM  500
#define HID    256
#define NCLASS 50
#define KHOPS  10
#define KPAD   512      // INDIM padded to multiple of 32 for MFMA
#define CPAD   64       // NCLASS padded (32 packed bf16 pairs per node row)

static inline size_t roundup256(size_t x) { return (x + 255) & ~(size_t)255; }

typedef __attribute__((ext_vector_type(8))) short bf16x8;   // 8 bf16 = 4 VGPRs
typedef __attribute__((ext_vector_type(4))) float f32x4;    // MFMA acc
typedef __attribute__((ext_vector_type(4))) short short4v;

typedef __attribute__((address_space(3))) unsigned       lds_u32;
typedef const __attribute__((address_space(1))) unsigned glb_u32;

__device__ inline short f2bf(float f) {      // fp32 -> bf16, round-nearest-even
    union { float f; unsigned u; } v; v.f = f;
    unsigned r = v.u + 0x7FFFu + ((v.u >> 16) & 1u);
    return (short)(r >> 16);
}
__device__ inline short f2bf_hw(float f) {   // HW cvt
    __hip_bfloat16 h = __float2bfloat16(f);
    return *reinterpret_cast<short*>(&h);
}
__device__ inline float bflo(unsigned u) {   // low bf16 of packed pair -> fp32
    union { unsigned u; float f; } v; v.u = u << 16; return v.f;
}
__device__ inline float bfhi(unsigned u) {   // high bf16 of packed pair -> fp32
    union { unsigned u; float f; } v; v.u = u & 0xFFFF0000u; return v.f;
}
__device__ inline unsigned packbf(float a, float b) {
    return (unsigned)(unsigned short)f2bf(a) | ((unsigned)(unsigned short)f2bf(b) << 16);
}

// ---------------------------------------------------------------------------
// prep: zero counters, degree, norm, scan, CSR fill
// ---------------------------------------------------------------------------
__global__ void dagnn_zero2(int* __restrict__ a, int* __restrict__ b, int n) {
    int i = blockIdx.x * blockDim.x + threadIdx.x;
    if (i < n) { a[i] = 0; b[i] = 0; }
}

__global__ void dagnn_deg(const int* __restrict__ dst, int* __restrict__ degi, int E) {
    int e = blockIdx.x * blockDim.x + threadIdx.x;
    if (e < E) atomicAdd(&degi[dst[e]], 1);
}

__global__ void dagnn_norm(const int* __restrict__ degi, float* __restrict__ nrm, int n) {
    int i = blockIdx.x * blockDim.x + threadIdx.x;
    if (i < n) nrm[i] = rsqrtf((float)degi[i]);   // deg >= 1 (self loop)
}

__global__ void dagnn_scan(const int* __restrict__ degi, int* __restrict__ rowptr, int n) {
    __shared__ int wsum[16];
    __shared__ int carry_s;
    const int tid  = threadIdx.x;        // 1024
    const int lane = tid & 63;
    const int wid  = tid >> 6;
    if (tid == 0) carry_s = 0;
    __syncthreads();
    for (int base = 0; base < n; base += 4096) {
        int i0 = base + tid * 4;
        int v0 = (i0 + 0 < n) ? degi[i0 + 0] : 0;
        int v1 = (i0 + 1 < n) ? degi[i0 + 1] : 0;
        int v2 = (i0 + 2 < n) ? degi[i0 + 2] : 0;
        int v3 = (i0 + 3 < n) ? degi[i0 + 3] : 0;
        int tsum = v0 + v1 + v2 + v3;
        int x = tsum;
        #pragma unroll
        for (int off = 1; off < 64; off <<= 1) {
            int t = __shfl_up(x, off);
            if (lane >= off) x += t;
        }
        if (lane == 63) wsum[wid] = x;
        __syncthreads();
        if (tid == 0) {
            int run = carry_s;
            #pragma unroll
            for (int w = 0; w < 16; ++w) { int t = wsum[w]; wsum[w] = run; run += t; }
            carry_s = run;
        }
        __syncthreads();
        int texcl = wsum[wid] + (x - tsum);
        if (i0 + 0 < n) rowptr[i0 + 0] = texcl;
        if (i0 + 1 < n) rowptr[i0 + 1] = texcl + v0;
        if (i0 + 2 < n) rowptr[i0 + 2] = texcl + v0 + v1;
        if (i0 + 3 < n) rowptr[i0 + 3] = texcl + v0 + v1 + v2;
        __syncthreads();
    }
    if (tid == 0) rowptr[n] = carry_s;
}

__global__ void dagnn_fill(const int* __restrict__ src, const int* __restrict__ dst,
                           const int* __restrict__ rowptr, int* __restrict__ fillc,
                           int* __restrict__ colidx, int E) {
    int e = blockIdx.x * blockDim.x + threadIdx.x;
    if (e >= E) return;
    int d = dst[e];
    int pos = rowptr[d] + atomicAdd(&fillc[d], 1);
    colidx[pos] = src[e];
}

// ---------------------------------------------------------------------------
// W1 [500][256] fp32 -> Bts: per-K-step pre-tiled bf16 layout.
// ---------------------------------------------------------------------------
__global__ void dagnn_w1ts(const float* __restrict__ W1, short* __restrict__ Bts) {
    int idx = blockIdx.x * 256 + threadIdx.x;   // 16*256*32 = 131072
    if (idx >= HID * KPAD) return;
    int ks = idx >> 13;          // K-step  0..15
    int n  = (idx >> 5) & 255;   // col     0..255
    int kk = idx & 31;           // k-in-tile
    int k  = ks * 32 + kk;
    float v = (k < INDIM) ? W1[(size_t)k * HID + n] : 0.f;
    Bts[idx] = f2bf(v);
}

// ---------------------------------------------------------------------------
// W2 [256][50] fp32 -> W2t [64][256] bf16 (transposed, zero-padded N)
// ---------------------------------------------------------------------------
__global__ void dagnn_w2t(const float* __restrict__ W2, short* __restrict__ W2t) {
    int idx = blockIdx.x * 256 + threadIdx.x;   // 64*256 = 16384
    if (idx >= CPAD * HID) return;
    int n = idx >> 8;         // 0..63
    int k = idx & 255;        // 0..255
    float v = (n < NCLASS) ? W2[(size_t)k * NCLASS + n] : 0.f;
    W2t[idx] = f2bf(v);
}

// sgate[c] = (s[2c], s[2c+1]) zero-padded; 32 entries
__global__ void dagnn_sgate(const float* __restrict__ svec, float2* __restrict__ sg) {
    int c = threadIdx.x;
    if (c < 32) {
        float x = (2 * c     < NCLASS) ? svec[2 * c]     : 0.f;
        float y = (2 * c + 1 < NCLASS) ? svec[2 * c + 1] : 0.f;
        sg[c] = make_float2(x, y);
    }
}

// ---------------------------------------------------------------------------
// GEMM1 (MFMA bf16): hid = relu(feats @ W1 + b1), bf16 out.
// 2-phase global_load_lds pipeline; A fp32 staged with XOR chunk-swizzle on
// the global source (linear LDS dest), matching XOR on the ds_read side;
// B staged from the pre-tiled Bts slab. Epilogue via LDS for 16B stores.
// block = 512 threads (8 waves); tile 128(M) x 256(N); BK=32.
// ---------------------------------------------------------------------------
#define G1_STAGE(ABASE, BBASE, KS)                                             \
    {                                                                          \
        const int k0_ = (KS) * 32;                                             \
        _Pragma("unroll")                                                      \
        for (int j = 0; j < 2; ++j) {                                          \
            int slot = (wid * 2 + j) * 64 + lane;                              \
            int mrow = slot >> 3;                 /* 0..127 */                 \
            int q    = (slot & 7) ^ (mrow & 7);   /* source chunk (swizzle) */ \
            int gm   = row0 + mrow;                                            \
            int gk   = k0_ + q * 4;                                            \
            const float* asrc = (gm < M && gk < INDIM)                         \
                ? (A + (size_t)gm * INDIM + gk) : A;                           \
            __builtin_amdgcn_global_load_lds((glb_u32*)asrc,                   \
                (lds_u32*)((ABASE) + (wid * 2 + j) * 256), 16, 0, 0);          \
            const short* bsrc = Bts + ((size_t)(KS) << 13) + slot * 8;         \
            __builtin_amdgcn_global_load_lds((glb_u32*)bsrc,                   \
                (lds_u32*)((BBASE) + (wid * 2 + j) * 512), 16, 0, 0);          \
        }                                                                      \
    }

__global__ __launch_bounds__(512, 4) void dagnn_gemm1_mfma(
        const float* __restrict__ A, const short* __restrict__ Bts,
        const float* __restrict__ bias, short* __restrict__ C, int M) {
    __shared__ __align__(16) char smem[67584];   // max(staging 64K, epi 66K)
    float* As0 = (float*)smem;                   // [128][32] f32, 16 KB
    float* As1 = (float*)(smem + 16384);
    short* Bs0 = (short*)(smem + 32768);         // [256][32] bf16, 16 KB
    short* Bs1 = (short*)(smem + 49152);
    short* Ep  = (short*)smem;                   // epilogue: [128][264] bf16

    const int tid  = threadIdx.x;
    const int lane = tid & 63;
    const int wid  = tid >> 6;              // 0..7
    const int l16  = lane & 15;
    const int quad = lane >> 4;             // 0..3
    const int m_off = (wid & 1) * 64;
    const int n_off = (wid >> 1) * 64;
    const int row0  = blockIdx.x * 128;

    f32x4 acc[4][4] = {};

    G1_STAGE(As0, Bs0, 0)
    __syncthreads();

    for (int ks = 0; ks < KPAD / 32; ++ks) {
        const int cur = ks & 1;
        const float* ab = cur ? As1 : As0;
        const short* bb = cur ? Bs1 : Bs0;
        if (ks + 1 < KPAD / 32) {
            if (cur) { G1_STAGE(As0, Bs0, ks + 1) }
            else     { G1_STAGE(As1, Bs1, ks + 1) }
        }

        bf16x8 bfr[4];
        #pragma unroll
        for (int nt = 0; nt < 4; ++nt)
            bfr[nt] = *(const bf16x8*)(bb + (n_off + nt * 16 + l16) * 32 + quad * 8);

        #pragma unroll
        for (int mt = 0; mt < 4; ++mt) {
            int m  = m_off + mt * 16 + l16;
            int s0 = (quad * 2 + 0) ^ (m & 7);       // swizzled chunk slots
            int s1 = (quad * 2 + 1) ^ (m & 7);
            float4 lo = *(const float4*)(ab + m * 32 + s0 * 4);
            float4 hi = *(const float4*)(ab + m * 32 + s1 * 4);
            bf16x8 af;
            af[0] = f2bf_hw(lo.x); af[1] = f2bf_hw(lo.y);
            af[2] = f2bf_hw(lo.z); af[3] = f2bf_hw(lo.w);
            af[4] = f2bf_hw(hi.x); af[5] = f2bf_hw(hi.y);
            af[6] = f2bf_hw(hi.z); af[7] = f2bf_hw(hi.w);
            #pragma unroll
            for (int nt = 0; nt < 4; ++nt)
                acc[mt][nt] = __builtin_amdgcn_mfma_f32_16x16x32_bf16(
                                  af, bfr[nt], acc[mt][nt], 0, 0, 0);
        }
        __syncthreads();      // drains vmcnt(0): next buffer staged + LDS free
    }

    // epilogue: bias + relu -> packed bf16 pairs into LDS, then coalesced out
    float bv[4];
    #pragma unroll
    for (int nt = 0; nt < 4; ++nt) bv[nt] = bias[n_off + nt * 16 + l16];

    #pragma unroll
    for (int mt = 0; mt < 4; ++mt) {
        #pragma unroll
        for (int nt = 0; nt < 4; ++nt) {
            #pragma unroll
            for (int r = 0; r < 4; ++r) {
                float v = acc[mt][nt][r] + bv[nt];
                v = v > 0.f ? v : 0.f;
                float vp = __shfl_xor(v, 1);          // partner column's value
                if (!(l16 & 1)) {
                    int mrel = m_off + mt * 16 + quad * 4 + r;
                    *(unsigned*)(Ep + mrel * 264 + n_off + nt * 16 + l16) =
                        packbf(v, vp);
                }
            }
        }
    }
    __syncthreads();
    #pragma unroll
    for (int it = 0; it < 8; ++it) {
        int cidx = tid + it * 512;          // 128 rows x 32 chunks of 16 B
        int rr   = cidx >> 5;
        int chk  = cidx & 31;
        int gm   = row0 + rr;
        if (gm < M)
            *(bf16x8*)(C + (size_t)gm * HID + chk * 8) =
                *(const bf16x8*)(Ep + rr * 264 + chk * 8);
    }
}

// ---------------------------------------------------------------------------
// GEMM2 (MFMA) + gate epilogue:
//   x = hid(bf16) @ W2 + b2 ; hs0 = packed-bf16(x*nrm) ; out = sigmoid(x.s)*x
// block = 256 threads (4 waves); tile 128(M) x 64(N); K=256, BK=64
// ---------------------------------------------------------------------------
#define A2_STRIDE 72
#define B2_STRIDE 264
__global__ __launch_bounds__(256) void dagnn_mlp2_mfma(
        const short* __restrict__ hid, const short* __restrict__ W2t,
        const float* __restrict__ b2, const float* __restrict__ svec,
        const float* __restrict__ nrm,
        unsigned* __restrict__ hs0, float* __restrict__ out, int M) {
    __shared__ __align__(16) short As[128 * A2_STRIDE];
    __shared__ __align__(16) short Bs[CPAD * B2_STRIDE];

    const int tid  = threadIdx.x;
    const int lane = tid & 63;
    const int wid  = tid >> 6;              // 0..3
    const int l16  = lane & 15;
    const int quad = lane >> 4;
    const int m_off = wid * 32;
    const int row0  = blockIdx.x * 128;

    // stage all of W2t (64 x 256) into LDS once
    #pragma unroll
    for (int it = 0; it < 8; ++it) {
        int slot = tid + it * 256;          // 0..2047
        int n   = slot >> 5;                // 0..63
        int seg = slot & 31;                // 8 bf16 each
        bf16x8 b = *(const bf16x8*)(W2t + (size_t)n * HID + seg * 8);
        *(bf16x8*)&Bs[n * B2_STRIDE + seg * 8] = b;
    }

    f32x4 acc[2][4] = {};

    for (int ks = 0; ks < HID / 64; ++ks) {     // 4 iterations, BK=64
        const int k0 = ks * 64;
        #pragma unroll
        for (int it = 0; it < 4; ++it) {
            int slot = tid + it * 256;      // 0..1023
            int m   = slot >> 3;            // 0..127
            int seg = slot & 7;             // 8 bf16 each
            int gm  = row0 + m;
            bf16x8 v = {};
            if (gm < M) v = *(const bf16x8*)(hid + (size_t)gm * HID + k0 + seg * 8);
            *(bf16x8*)&As[m * A2_STRIDE + seg * 8] = v;
        }
        __syncthreads();

        #pragma unroll
        for (int ksub = 0; ksub < 2; ++ksub) {
            bf16x8 af[2], bfr[4];
            #pragma unroll
            for (int mt = 0; mt < 2; ++mt)
                af[mt] = *(const bf16x8*)&As[(m_off + mt * 16 + l16) * A2_STRIDE
                                             + ksub * 32 + quad * 8];
            #pragma unroll
            for (int nt = 0; nt < 4; ++nt)
                bfr[nt] = *(const bf16x8*)&Bs[(nt * 16 + l16) * B2_STRIDE
                                              + k0 + ksub * 32 + quad * 8];
            #pragma unroll
            for (int mt = 0; mt < 2; ++mt)
                #pragma unroll
                for (int nt = 0; nt < 4; ++nt)
                    acc[mt][nt] = __builtin_amdgcn_mfma_f32_16x16x32_bf16(
                                      af[mt], bfr[nt], acc[mt][nt], 0, 0, 0);
        }
        __syncthreads();
    }

    float b2v[4], ssv[4];
    #pragma unroll
    for (int nt = 0; nt < 4; ++nt) {
        int gc = nt * 16 + l16;
        b2v[nt] = (gc < NCLASS) ? b2[gc]   : 0.f;
        ssv[nt] = (gc < NCLASS) ? svec[gc] : 0.f;
    }
    #pragma unroll
    for (int mt = 0; mt < 2; ++mt) {
        #pragma unroll
        for (int r = 0; r < 4; ++r) {
            int gm = row0 + m_off + mt * 16 + quad * 4 + r;
            float xv[4], q = 0.f;
            #pragma unroll
            for (int nt = 0; nt < 4; ++nt) {
                xv[nt] = acc[mt][nt][r] + b2v[nt];
                q += xv[nt] * ssv[nt];
            }
            #pragma unroll
            for (int off = 1; off < 16; off <<= 1) q += __shfl_xor(q, off);
            float S = 1.f / (1.f + __expf(-q));
            float nd = (gm < M) ? nrm[gm] : 0.f;
            #pragma unroll
            for (int nt = 0; nt < 4; ++nt) {
                int gc = nt * 16 + l16;
                float hv = xv[nt] * nd;
                float hp = __shfl_xor(hv, 1);     // partner lane's value
                if (gm < M) {
                    if (!(l16 & 1))               // even lane packs (gc, gc+1)
                        hs0[(size_t)gm * 32 + nt * 8 + (l16 >> 1)] = packbf(hv, hp);
                    if (gc < NCLASS) out[(size_t)gm * NCLASS + gc] = S * xv[nt];
                }
            }
        }
    }
}

// ---------------------------------------------------------------------------
// propagation hop (packed bf16 rows, 128 B/node):
//   r[d]       = nrm[d] * sum_{s in N(d)} hs[s]       (fp32 accumulate)
//   hs_next[d] = packed-bf16(r * nrm[d])
//   out[d]    += sigmoid(r . s) * r
// prop7: one wave per dst row, half-wave per edge stream. 16 edges per
// iteration (8 gathers in flight per half-wave = 16/wave, 2x prop4's MLP).
// Tail handled by ONE guarded 16-edge block (no serial 2-edge drain).
// colidx loads non-temporal (stream; preserve L2 for hs). out-row RMW read
// hoisted above the gather chain.
// ---------------------------------------------------------------------------
__global__ __launch_bounds__(256) void dagnn_prop7(
        const unsigned* __restrict__ hs, const float* __restrict__ nrm,
        const int* __restrict__ rowptr, const int* __restrict__ colidx,
        const float2* __restrict__ sgate, unsigned* __restrict__ hs_next,
        float* __restrict__ out, int M, int write_next) {
    const int lane = threadIdx.x & 63;
    const int wid  = threadIdx.x >> 6;
    const int d    = blockIdx.x * 4 + wid;
    if (d >= M) return;
    const int half = lane >> 5;         // edge-parity stream (0: even, 1: odd)
    const int c    = lane & 31;         // channel-pair index (ch 2c, 2c+1)
    const int beg = rowptr[d], end = rowptr[d + 1];
    const float nd = nrm[d];

    // prefetch out row (RMW read issued before the gather chain)
    const int ch = 2 * c;
    float o0 = 0.f, o1 = 0.f;
    if (half == 0 && ch < NCLASS) {
        o0 = out[(size_t)d * NCLASS + ch];
        o1 = out[(size_t)d * NCLASS + ch + 1];
    }

    float a0 = 0.f, a1 = 0.f;
    int e = beg;
    // main: 16 edges per iteration, unguarded (8 gathers in flight per half)
    for (; e + 16 <= end; e += 16) {
        int s[8];
        #pragma unroll
        for (int t = 0; t < 8; ++t)
            s[t] = __builtin_nontemporal_load(&colidx[e + half + 2 * t]);
        unsigned u[8];
        #pragma unroll
        for (int t = 0; t < 8; ++t)
            u[t] = hs[(size_t)s[t] * 32 + c];
        #pragma unroll
        for (int t = 0; t < 8; ++t) { a0 += bflo(u[t]); a1 += bfhi(u[t]); }
    }
    // tail: one guarded 16-edge block covers the remaining <16 edges
    if (e < end) {
        int s[8];
        #pragma unroll
        for (int t = 0; t < 8; ++t) {
            int ei = e + half + 2 * t;
            s[t] = (ei < end) ? __builtin_nontemporal_load(&colidx[ei]) : -1;
        }
        #pragma unroll
        for (int t = 0; t < 8; ++t) {
            if (s[t] >= 0) {
                unsigned u = hs[(size_t)s[t] * 32 + c];
                a0 += bflo(u); a1 += bfhi(u);
            }
        }
    }

    a0 += __shfl_xor(a0, 32);           // combine the two half-wave partials
    a1 += __shfl_xor(a1, 32);

    float r0 = a0 * nd, r1 = a1 * nd;
    float2 g = sgate[c];
    float p = r0 * g.x + r1 * g.y;
    #pragma unroll
    for (int off = 16; off; off >>= 1) p += __shfl_xor(p, off);  // 32-lane sum
    float S = 1.f / (1.f + __expf(-p));
    if (half == 0) {
        if (write_next) hs_next[(size_t)d * 32 + c] = packbf(r0 * nd, r1 * nd);
        if (ch < NCLASS) {
            out[(size_t)d * NCLASS + ch]     = o0 + S * r0;
            out[(size_t)d * NCLASS + ch + 1] = o1 + S * r1;
        }
    }
}

// ---------------------------------------------------------------------------
extern "C" void kernel_launch(void* const* d_in, const int* in_sizes, int n_in,
                              void* d_out, int out_size, void* d_ws, size_t ws_size,
                              hipStream_t stream) {
    const float* feats = (const float*)d_in[0];
    const float* W1    = (const float*)d_in[1];
    const float* b1    = (const float*)d_in[2];
    const float* W2    = (const float*)d_in[3];
    const float* b2    = (const float*)d_in[4];
    const float* svec  = (const float*)d_in[5];
    const int*   src   = (const int*)d_in[6];
    const int*   dst   = (const int*)d_in[7];
    float* out = (float*)d_out;

    const int M = in_sizes[0] / INDIM;    // 100000
    const int E = in_sizes[6];            // 1600000

    // workspace carve-up
    char* p = (char*)d_ws;
    size_t off = 0;
    short*    hid   = (short*)   (p + off); off += roundup256((size_t)M * HID * 2);
    unsigned* hsA   = (unsigned*)(p + off); off += roundup256((size_t)M * 32 * 4);
    unsigned* hsB   = (unsigned*)(p + off); off += roundup256((size_t)M * 32 * 4);
    short*    W1t   = (short*)   (p + off); off += roundup256((size_t)HID * KPAD * 2);
    short*    W2t   = (short*)   (p + off); off += roundup256((size_t)CPAD * HID * 2);
    float2*   sgate = (float2*)  (p + off); off += roundup256(32 * sizeof(float2));
    int*      degi  = (int*)     (p + off); off += roundup256((size_t)M * 4);
    float*    nrm   = (float*)   (p + off); off += roundup256((size_t)M * 4);
    int*      rowptr= (int*)     (p + off); off += roundup256((size_t)(M + 1) * 4);
    int*      fillc = (int*)     (p + off); off += roundup256((size_t)M * 4);
    int*      colidx= (int*)     (p + off); off += roundup256((size_t)E * 4);
    (void)ws_size;

    // --- graph/degree prep ---
    dagnn_zero2<<<(M + 255) / 256, 256, 0, stream>>>(degi, fillc, M);
    dagnn_deg<<<(E + 255) / 256, 256, 0, stream>>>(dst, degi, E);
    dagnn_norm<<<(M + 255) / 256, 256, 0, stream>>>(degi, nrm, M);
    dagnn_scan<<<1, 1024, 0, stream>>>(degi, rowptr, M);
    dagnn_fill<<<(E + 255) / 256, 256, 0, stream>>>(src, dst, rowptr, fillc, colidx, E);

    // --- weight prep ---
    dagnn_w1ts<<<(HID * KPAD + 255) / 256, 256, 0, stream>>>(W1, W1t);
    dagnn_w2t<<<(CPAD * HID + 255) / 256, 256, 0, stream>>>(W2, W2t);
    dagnn_sgate<<<1, 32, 0, stream>>>(svec, sgate);

    // --- MLP ---
    dagnn_gemm1_mfma<<<(M + 127) / 128, 512, 0, stream>>>(feats, W1t, b1, hid, M);
    dagnn_mlp2_mfma<<<(M + 127) / 128, 256, 0, stream>>>(hid, W2t, b2, svec, nrm,
                                                         hsA, out, M);

    // --- K propagation hops with online output accumulation ---
    unsigned* hin = hsA;
    unsigned* hout = hsB;
    for (int k = 0; k < KHOPS; ++k) {
        dagnn_prop7<<<(M + 3) / 4, 256, 0, stream>>>(hin, nrm, rowptr, colidx,
                                                     sgate, hout, out, M,
                                                     k < KHOPS - 1);
        unsigned* t = hin; hin = hout; hout = t;
    }
}